// Round 4
// baseline (462.871 us; speedup 1.0000x reference)
//
#include <hip/hip_runtime.h>

#define HW 4096
#define DECAYF 0.99f
#define ONEMF 0.01f
#define EPSF 1e-5f
#define BIAS 192.0f

typedef __bf16 bf16x8 __attribute__((ext_vector_type(8)));
typedef float f32x4 __attribute__((ext_vector_type(4)));
typedef unsigned short ushort8 __attribute__((ext_vector_type(8)));

// ws float layout:
// [0, 1048576)           dw accumulator, 16 replicas of K*D
// [1048576, 1049600)     counts (K)
// [1049600, 1050624)     nchalf = -0.5*||e_k||^2
// [1050624]              sse
// [1050640, 1083408)     E_hi bf16 (ushort) [K][D]
// [1083408, 1116176)     E_lo bf16 (ushort)
#define WS_DW     0
#define WS_COUNTS 1048576
#define WS_NCHALF 1049600
#define WS_SSE    1050624
#define WS_EHI    1050640
#define WS_ELO    1083408

__device__ __forceinline__ float wave_reduce_add(float v) {
#pragma unroll
    for (int o = 32; o > 0; o >>= 1) v += __shfl_xor(v, o, 64);
    return v;
}

__device__ __forceinline__ unsigned short bf_rne(float f) {
    unsigned int u = __float_as_uint(f);
    unsigned int r = u + 0x7fffu + ((u >> 16) & 1u);
    return (unsigned short)(r >> 16);
}

__device__ __forceinline__ unsigned med3u(unsigned a, unsigned b, unsigned c) {
    // median of three -> v_med3_u32 (or 4 min/max)
    unsigned mn = a < b ? a : b;
    unsigned mx = a > b ? a : b;
    unsigned t = mx < c ? mx : c;
    return mn > t ? mn : t;
}

// Zero dw replicas/counts/sse; split E into bf16 hi/lo; nchalf. grid 4096 x 256.
__global__ __launch_bounds__(256) void prep_kernel(const float* __restrict__ E,
                                                   float* __restrict__ ws) {
    const int bid = blockIdx.x, tid = threadIdx.x;
    const int id = bid * 256 + tid;
    ws[WS_DW + id] = 0.0f;                       // 16 replicas, 1,048,576 floats exactly
    if (bid < 4) ws[WS_COUNTS + bid * 256 + tid] = 0.0f;
    if (bid == 4 && tid == 0) ws[WS_SSE] = 0.0f;
    if (bid < 256) {                             // E split: 65536 elements
        const float v = E[id];
        const unsigned short h = bf_rne(v);
        const float hf = __uint_as_float((unsigned int)h << 16);
        const unsigned short l = bf_rne(v - hf);
        ((unsigned short*)(ws + WS_EHI))[id] = h;
        ((unsigned short*)(ws + WS_ELO))[id] = l;
        const float s = wave_reduce_add(v * v);
        if ((tid & 63) == 0) ws[WS_NCHALF + (id >> 6)] = -0.5f * s;
    }
}

// Main: MFMA scores + packed top-2 + fp64 re-rank + scatter outputs.
// grid 1024 x 256; each block = 64 tokens; each wave = one 16-token tile x all 1024 codes.
__global__ __launch_bounds__(256) void vq_main(const float* __restrict__ x,
                                               const float* __restrict__ E,
                                               float* __restrict__ out,
                                               float* __restrict__ ws) {
    const int tid = threadIdx.x;
    const int lane = tid & 63;
    const int w = tid >> 6;
    const int q = lane >> 4, m = lane & 15;
    const int blk = blockIdx.x;
    const int bb = blk >> 6;           // batch
    const int hw0 = (blk & 63) << 6;   // hw offset (64 tokens)
    const int tok0 = blk << 6;

    __shared__ float xs[64 * 68];      // [token][dim], 16B-aligned rows
    __shared__ unsigned t1s[4][16][16], t2s[4][16][16];
    __shared__ int idx_sh[64];

    // Stage x tile (coalesced: consecutive tid -> consecutive hw).
    {
        const float* xb = x + ((size_t)bb << 18) + hw0;
#pragma unroll
        for (int cc = 0; cc < 16; ++cc) {
            const int id = cc * 256 + tid;
            const int c = id >> 6, t = id & 63;
            xs[t * 68 + c] = xb[((size_t)c << 12) + t];
        }
    }
    __syncthreads();

    // A fragments: 1 row-tile (16 tokens) x 2 K-slices x (hi,lo).
    bf16x8 Ah[2], Al[2];
    {
        const int tok = w * 16 + m;
#pragma unroll
        for (int s = 0; s < 2; ++s) {
            const float* p = &xs[tok * 68 + s * 32 + q * 8];
            ushort8 hu, lu;
#pragma unroll
            for (int j = 0; j < 8; ++j) {
                const float f = p[j];
                const unsigned short h = bf_rne(f);
                const float hf = __uint_as_float((unsigned int)h << 16);
                hu[j] = h;
                lu[j] = bf_rne(f - hf);
            }
            Ah[s] = __builtin_bit_cast(bf16x8, hu);
            Al[s] = __builtin_bit_cast(bf16x8, lu);
        }
    }

    const ushort8* __restrict__ Ehp = (const ushort8*)(ws + WS_EHI);
    const ushort8* __restrict__ Elp = (const ushort8*)(ws + WS_ELO);
    const float* __restrict__ ncp = ws + WS_NCHALF;

    // Packed top-2 per C/D row: fp32 bits of (score+BIAS) are monotone-unsigned
    // (score+BIAS in ~[100,220] > 0); low 6 bits = ck, lane m implied.
    unsigned b1[4] = {0, 0, 0, 0}, b2[4] = {0, 0, 0, 0};

    ushort8 nb0h = Ehp[m * 8 + q];
    ushort8 nb1h = Ehp[m * 8 + 4 + q];
    ushort8 nb0l = Elp[m * 8 + q];
    ushort8 nb1l = Elp[m * 8 + 4 + q];
    float nnc = ncp[m];

    for (int ck = 0; ck < 64; ++ck) {
        const ushort8 c0h = nb0h, c1h = nb1h, c0l = nb0l, c1l = nb1l;
        const float nc = nnc;
        if (ck < 63) {
            const int code = (ck + 1) * 16 + m;
            nb0h = Ehp[code * 8 + q];
            nb1h = Ehp[code * 8 + 4 + q];
            nb0l = Elp[code * 8 + q];
            nb1l = Elp[code * 8 + 4 + q];
            nnc = ncp[code];
        }
        const bf16x8 bh0 = __builtin_bit_cast(bf16x8, c0h);
        const bf16x8 bh1 = __builtin_bit_cast(bf16x8, c1h);
        const bf16x8 bl0 = __builtin_bit_cast(bf16x8, c0l);
        const bf16x8 bl1 = __builtin_bit_cast(bf16x8, c1l);
        const float base = nc + BIAS;
        f32x4 acc_a = {base, base, base, base};   // K-slice 0 chain
        f32x4 acc_b = {0.f, 0.f, 0.f, 0.f};      // K-slice 1 chain (independent)
        acc_a = __builtin_amdgcn_mfma_f32_16x16x32_bf16(Ah[0], bh0, acc_a, 0, 0, 0);
        acc_b = __builtin_amdgcn_mfma_f32_16x16x32_bf16(Ah[1], bh1, acc_b, 0, 0, 0);
        acc_a = __builtin_amdgcn_mfma_f32_16x16x32_bf16(Al[0], bh0, acc_a, 0, 0, 0);
        acc_b = __builtin_amdgcn_mfma_f32_16x16x32_bf16(Al[1], bh1, acc_b, 0, 0, 0);
        acc_a = __builtin_amdgcn_mfma_f32_16x16x32_bf16(Ah[0], bl0, acc_a, 0, 0, 0);
        acc_b = __builtin_amdgcn_mfma_f32_16x16x32_bf16(Ah[1], bl1, acc_b, 0, 0, 0);
#pragma unroll
        for (int r = 0; r < 4; ++r) {
            const float s = acc_a[r] + acc_b[r];
            const unsigned p = (__float_as_uint(s) & ~63u) | (unsigned)ck;
            b2[r] = med3u(b1[r], b2[r], p);       // new 2nd (uses old b1)
            b1[r] = b1[r] > p ? b1[r] : p;        // new 1st
        }
    }

    // Publish per-lane top-2 to LDS; same-wave merge (no barrier needed).
#pragma unroll
    for (int r = 0; r < 4; ++r) {
        t1s[w][q * 4 + r][m] = b1[r];
        t2s[w][q * 4 + r][m] = b2[r];
    }

    float dval = 0.0f;
    if (lane < 16) {
        // Merge the 16 column-groups for token tokL = w*16+lane.
        unsigned s1 = 0, s2 = 0;
        int c1 = 0, c2 = 0;
#pragma unroll 4
        for (int mm = 0; mm < 16; ++mm) {
            const unsigned a = t1s[w][lane][mm];
            const int codeA = (int)((a & 63u) << 4) | mm;
            if (a > s1) { s2 = s1; c2 = c1; s1 = a; c1 = codeA; }
            else if (a > s2) { s2 = a; c2 = codeA; }
            const unsigned bsec = t2s[w][lane][mm];   // <= a, can only contend for 2nd
            if (bsec > s2) { s2 = bsec; c2 = (int)((bsec & 63u) << 4) | mm; }
        }
        // fp64 re-rank of the two candidates.
        const int tokL = w * 16 + lane;
        const int ca = c1 < c2 ? c1 : c2;
        const int cb = c1 < c2 ? c2 : c1;
        const float* Ea = E + ca * 64;
        const float* Eb = E + cb * 64;
        const float* xr = &xs[tokL * 68];
        double sa = 0, ea = 0, sb = 0, eb = 0, x2 = 0;
#pragma unroll 8
        for (int c = 0; c < 64; ++c) {
            const double xv = (double)xr[c];
            const double va = (double)Ea[c], vb = (double)Eb[c];
            sa += xv * va; ea += va * va;
            sb += xv * vb; eb += vb * vb;
            x2 += xv * xv;
        }
        const double qa = ea - 2.0 * sa;
        const double qb = eb - 2.0 * sb;
        int best; double qq;
        if (qb < qa) { best = cb; qq = qb; } else { best = ca; qq = qa; }
        idx_sh[tokL] = best;
        float dd = (float)(qq + x2);
        dval = dd < 0.f ? 0.f : dd;
        atomicAdd(&ws[WS_COUNTS + best], 1.0f);
    }
    const float ssum = wave_reduce_add(dval);
    if (lane == 0) atomicAdd(&ws[WS_SSE], ssum);
    __syncthreads();

    // q_st output (reference order: x + (e - x)).
    float* outq = out + 1;
#pragma unroll
    for (int cc = 0; cc < 16; ++cc) {
        const int id = cc * 256 + tid;
        const int c = id >> 6, t = id & 63;
        const int kb = idx_sh[t];
        const float xv = xs[t * 68 + c];
        const float eq = E[kb * 64 + c];
        outq[((size_t)(bb * 64 + c) << 12) + hw0 + t] = xv + (eq - xv);
    }
    // dw scatter-add into replica (blk & 15): lane = dim, wave-uniform row.
    {
        float* dwr = ws + WS_DW + (size_t)(blk & 15) * 65536;
#pragma unroll 4
        for (int tt = 0; tt < 16; ++tt) {
            const int t = w * 16 + tt;
            const int kb = idx_sh[t];
            atomicAdd(&dwr[kb * 64 + lane], xs[t * 68 + lane]);
        }
    }
    // one-hot encodings: one f32x4 nontemporal store per thread per row.
    {
        float* enc = out + 1 + (size_t)4194304;
        const int c0 = tid << 2;
        for (int t = 0; t < 64; ++t) {
            const int kb = idx_sh[t];
            f32x4 v;
            v[0] = (c0 == kb) ? 1.0f : 0.0f;
            v[1] = (c0 + 1 == kb) ? 1.0f : 0.0f;
            v[2] = (c0 + 2 == kb) ? 1.0f : 0.0f;
            v[3] = (c0 + 3 == kb) ? 1.0f : 0.0f;
            __builtin_nontemporal_store(v, (f32x4*)(enc + (size_t)(tok0 + t) * 1024 + c0));
        }
    }
}

// new_cs (Laplace-smoothed) + loss. 1 block x 1024.
__global__ __launch_bounds__(1024) void fin_cs(const float* __restrict__ cs_in,
                                               float* __restrict__ out,
                                               const float* __restrict__ ws) {
    __shared__ float red[16];
    __shared__ float n_sh;
    const int tid = threadIdx.x;
    const float raw = cs_in[tid] * DECAYF + ONEMF * ws[WS_COUNTS + tid];
    const float s = wave_reduce_add(raw);
    if ((tid & 63) == 0) red[tid >> 6] = s;
    __syncthreads();
    if (tid == 0) {
        float n = 0.f;
#pragma unroll
        for (int i = 0; i < 16; ++i) n += red[i];
        n_sh = n;
        out[0] = 0.25f * ws[WS_SSE] * (1.0f / 4194304.0f);  // loss
    }
    __syncthreads();
    const float n = n_sh;
    out[71368705 + tid] = (raw + EPSF) / (n + 1024.0f * EPSF) * n;
}

// new_ema_weight and new_embedding (reduce 16 dw replicas). grid 256 x 256.
__global__ __launch_bounds__(256) void fin_w(const float* __restrict__ emaw,
                                             float* __restrict__ out,
                                             const float* __restrict__ ws) {
    const int i = blockIdx.x * 256 + threadIdx.x;
    float acc = 0.f;
#pragma unroll
    for (int p = 0; p < 16; ++p) acc += ws[WS_DW + p * 65536 + i];
    const float val = emaw[i] * DECAYF + ONEMF * acc;
    out[71369729 + i] = val;                               // new_ema_weight
    const float cs = out[71368705 + (i >> 6)];             // new_cs (from fin_cs)
    out[71303169 + i] = val / cs;                          // new_embedding
}

extern "C" void kernel_launch(void* const* d_in, const int* in_sizes, int n_in,
                              void* d_out, int out_size, void* d_ws, size_t ws_size,
                              hipStream_t stream) {
    const float* x    = (const float*)d_in[0];   // [16,64,64,64]
    const float* E    = (const float*)d_in[1];   // [1024,64]
    const float* cs   = (const float*)d_in[2];   // [1024]
    const float* emaw = (const float*)d_in[3];   // [1024,64]
    float* out = (float*)d_out;
    float* ws  = (float*)d_ws;

    prep_kernel<<<4096, 256, 0, stream>>>(E, ws);
    vq_main<<<1024, 256, 0, stream>>>(x, E, out, ws);
    fin_cs<<<1, 1024, 0, stream>>>(cs, out, ws);
    fin_w<<<256, 256, 0, stream>>>(emaw, out, ws);
}

// Round 5
// 422.941 us; speedup vs baseline: 1.0944x; 1.0944x over previous
//
#include <hip/hip_runtime.h>

#define HW 4096
#define DECAYF 0.99f
#define ONEMF 0.01f
#define EPSF 1e-5f
#define BIAS 192.0f

typedef __bf16 bf16x8 __attribute__((ext_vector_type(8)));
typedef float f32x4 __attribute__((ext_vector_type(4)));
typedef unsigned short ushort8 __attribute__((ext_vector_type(8)));

// ws float layout:
// [0, 1048576)            dw accumulator, 16 replicas of K*D
// [1048576, 1064960)      counts, 16 replicas of K
// [1064960, 1065984)      nchalf = -0.5*||e_k||^2
// [1065984]               sse
// [1066000, 1131536)      idx (int) per token, 65536
// [1131536, 1164304)      E_hi bf16 (ushort) [K][D]
// [1164304, 1197072)      E_lo bf16 (ushort)
#define WS_DW     0
#define WS_COUNTS 1048576
#define WS_NCHALF 1064960
#define WS_SSE    1065984
#define WS_IDX    1066000
#define WS_EHI    1131536
#define WS_ELO    1164304

__device__ __forceinline__ float wave_reduce_add(float v) {
#pragma unroll
    for (int o = 32; o > 0; o >>= 1) v += __shfl_xor(v, o, 64);
    return v;
}

__device__ __forceinline__ unsigned short bf_rne(float f) {
    unsigned int u = __float_as_uint(f);
    unsigned int r = u + 0x7fffu + ((u >> 16) & 1u);
    return (unsigned short)(r >> 16);
}

__device__ __forceinline__ unsigned med3u(unsigned a, unsigned b, unsigned c) {
    unsigned mn = a < b ? a : b;
    unsigned mx = a > b ? a : b;
    unsigned t = mx < c ? mx : c;
    return mn > t ? mn : t;
}

// Zero dw/counts (contiguous 1,064,960 floats) + sse; E split; nchalf.
// grid 4160 x 256 (4160*256 == 1064960 exactly).
__global__ __launch_bounds__(256) void prep_kernel(const float* __restrict__ E,
                                                   float* __restrict__ ws) {
    const int bid = blockIdx.x, tid = threadIdx.x;
    const int id = bid * 256 + tid;
    ws[id] = 0.0f;                               // dw + counts replicas
    if (bid == 0 && tid == 0) ws[WS_SSE] = 0.0f;
    if (bid < 256) {                             // E split: 65536 elements
        const float v = E[id];
        const unsigned short h = bf_rne(v);
        const float hf = __uint_as_float((unsigned int)h << 16);
        const unsigned short l = bf_rne(v - hf);
        ((unsigned short*)(ws + WS_EHI))[id] = h;
        ((unsigned short*)(ws + WS_ELO))[id] = l;
        const float s = wave_reduce_add(v * v);
        if ((tid & 63) == 0) ws[WS_NCHALF + (id >> 6)] = -0.5f * s;
    }
}

// Main: MFMA scores + packed top-2 + fp64 re-rank + idx/counts/sse/q_st/dw.
// grid 512 x 256; block = 128 tokens; wave = 32 tokens (2 tiles) x 1024 codes.
__global__ __launch_bounds__(256) void vq_main(const float* __restrict__ x,
                                               const float* __restrict__ E,
                                               float* __restrict__ out,
                                               float* __restrict__ ws) {
    const int tid = threadIdx.x;
    const int lane = tid & 63;
    const int w = tid >> 6;
    const int q = lane >> 4, m = lane & 15;
    const int blk = blockIdx.x;
    const int bb = blk >> 5;           // batch
    const int hw0 = (blk & 31) << 7;   // hw offset (128 tokens)
    const int tok0 = blk << 7;

    __shared__ float xs[128 * 68];     // [token][dim], rows 16B-aligned (68*4=272)
    __shared__ unsigned t1s[4][32][16], t2s[4][32][16];
    __shared__ int idx_sh[128];

    // Stage x tile (coalesced).
    {
        const float* xb = x + ((size_t)bb << 18) + hw0;
#pragma unroll
        for (int cc = 0; cc < 32; ++cc) {
            const int id = cc * 256 + tid;
            const int c = id >> 7, t = id & 127;
            xs[t * 68 + c] = xb[((size_t)c << 12) + t];
        }
    }
    __syncthreads();

    // A fragments: 2 row-tiles x 2 K-slices x (hi,lo).
    bf16x8 Ah[2][2], Al[2][2];
#pragma unroll
    for (int t = 0; t < 2; ++t) {
        const int tok = w * 32 + t * 16 + m;
#pragma unroll
        for (int s = 0; s < 2; ++s) {
            const float* p = &xs[tok * 68 + s * 32 + q * 8];
            ushort8 hu, lu;
#pragma unroll
            for (int j = 0; j < 8; ++j) {
                const float f = p[j];
                const unsigned short h = bf_rne(f);
                const float hf = __uint_as_float((unsigned int)h << 16);
                hu[j] = h;
                lu[j] = bf_rne(f - hf);
            }
            Ah[t][s] = __builtin_bit_cast(bf16x8, hu);
            Al[t][s] = __builtin_bit_cast(bf16x8, lu);
        }
    }

    const ushort8* __restrict__ Ehp = (const ushort8*)(ws + WS_EHI);
    const ushort8* __restrict__ Elp = (const ushort8*)(ws + WS_ELO);
    const float* __restrict__ ncp = ws + WS_NCHALF;

    // Packed top-2 per C/D row: fp32 bits of (score+BIAS) monotone-unsigned;
    // low 6 bits = ck (code = ck*16 + m).
    unsigned b1[2][4] = {{0,0,0,0},{0,0,0,0}}, b2[2][4] = {{0,0,0,0},{0,0,0,0}};

    ushort8 nb0h = Ehp[m * 8 + q];
    ushort8 nb1h = Ehp[m * 8 + 4 + q];
    ushort8 nb0l = Elp[m * 8 + q];
    ushort8 nb1l = Elp[m * 8 + 4 + q];
    float nnc = ncp[m];

    for (int ck = 0; ck < 64; ++ck) {
        const ushort8 c0h = nb0h, c1h = nb1h, c0l = nb0l, c1l = nb1l;
        const float nc = nnc;
        if (ck < 63) {
            const int code = (ck + 1) * 16 + m;
            nb0h = Ehp[code * 8 + q];
            nb1h = Ehp[code * 8 + 4 + q];
            nb0l = Elp[code * 8 + q];
            nb1l = Elp[code * 8 + 4 + q];
            nnc = ncp[code];
        }
        const bf16x8 bh0 = __builtin_bit_cast(bf16x8, c0h);
        const bf16x8 bh1 = __builtin_bit_cast(bf16x8, c1h);
        const bf16x8 bl0 = __builtin_bit_cast(bf16x8, c0l);
        const bf16x8 bl1 = __builtin_bit_cast(bf16x8, c1l);
        const float base = nc + BIAS;
#pragma unroll
        for (int t = 0; t < 2; ++t) {
            f32x4 acc = {base, base, base, base};
            acc = __builtin_amdgcn_mfma_f32_16x16x32_bf16(Ah[t][0], bh0, acc, 0, 0, 0);
            acc = __builtin_amdgcn_mfma_f32_16x16x32_bf16(Ah[t][1], bh1, acc, 0, 0, 0);
            acc = __builtin_amdgcn_mfma_f32_16x16x32_bf16(Al[t][0], bh0, acc, 0, 0, 0);
            acc = __builtin_amdgcn_mfma_f32_16x16x32_bf16(Al[t][1], bh1, acc, 0, 0, 0);
            acc = __builtin_amdgcn_mfma_f32_16x16x32_bf16(Ah[t][0], bl0, acc, 0, 0, 0);
            acc = __builtin_amdgcn_mfma_f32_16x16x32_bf16(Ah[t][1], bl1, acc, 0, 0, 0);
#pragma unroll
            for (int r = 0; r < 4; ++r) {
                const unsigned p = (__float_as_uint(acc[r]) & ~63u) | (unsigned)ck;
                b2[t][r] = med3u(b1[t][r], b2[t][r], p);
                b1[t][r] = b1[t][r] > p ? b1[t][r] : p;
            }
        }
    }

    // Publish per-lane top-2; same-wave LDS merge.
#pragma unroll
    for (int t = 0; t < 2; ++t)
#pragma unroll
        for (int r = 0; r < 4; ++r) {
            t1s[w][t * 16 + q * 4 + r][m] = b1[t][r];
            t2s[w][t * 16 + q * 4 + r][m] = b2[t][r];
        }

    float dval = 0.0f;
    if (lane < 32) {
        unsigned s1 = 0, s2 = 0;
        int c1 = 0, c2 = 0;
#pragma unroll 4
        for (int mm = 0; mm < 16; ++mm) {
            const unsigned a = t1s[w][lane][mm];
            const int codeA = (int)((a & 63u) << 4) | mm;
            if (a > s1) { s2 = s1; c2 = c1; s1 = a; c1 = codeA; }
            else if (a > s2) { s2 = a; c2 = codeA; }
            const unsigned bsec = t2s[w][lane][mm];
            if (bsec > s2) { s2 = bsec; c2 = (int)((bsec & 63u) << 4) | mm; }
        }
        // fp64 re-rank (vectorized f32x4 loads).
        const int tokL = w * 32 + lane;
        const int ca = c1 < c2 ? c1 : c2;
        const int cb = c1 < c2 ? c2 : c1;
        const f32x4* Ea4 = (const f32x4*)(E + ca * 64);
        const f32x4* Eb4 = (const f32x4*)(E + cb * 64);
        const f32x4* xr4 = (const f32x4*)(&xs[tokL * 68]);
        double sa = 0, ea = 0, sb = 0, eb = 0, x2 = 0;
#pragma unroll 4
        for (int c4 = 0; c4 < 16; ++c4) {
            const f32x4 ev = Ea4[c4], fv = Eb4[c4], xv4 = xr4[c4];
#pragma unroll
            for (int j = 0; j < 4; ++j) {
                const double xv = (double)xv4[j];
                const double va = (double)ev[j], vb = (double)fv[j];
                sa += xv * va; ea += va * va;
                sb += xv * vb; eb += vb * vb;
                x2 += xv * xv;
            }
        }
        const double qa = ea - 2.0 * sa;
        const double qb = eb - 2.0 * sb;
        int best; double qq;
        if (qb < qa) { best = cb; qq = qb; } else { best = ca; qq = qa; }
        idx_sh[tokL] = best;
        ((int*)(ws + WS_IDX))[tok0 + tokL] = best;
        float dd = (float)(qq + x2);
        dval = dd < 0.f ? 0.f : dd;
        atomicAdd(&ws[WS_COUNTS + (blk & 15) * 1024 + best], 1.0f);
    }
    const float ssum = wave_reduce_add(dval);
    if (lane == 0) atomicAdd(&ws[WS_SSE], ssum);
    __syncthreads();

    // q_st output (reference order: x + (e - x)).
    float* outq = out + 1;
#pragma unroll
    for (int cc = 0; cc < 32; ++cc) {
        const int id = cc * 256 + tid;
        const int c = id >> 7, t = id & 127;
        const int kb = idx_sh[t];
        const float xv = xs[t * 68 + c];
        const float eq = E[kb * 64 + c];
        outq[((size_t)(bb * 64 + c) << 12) + hw0 + t] = xv + (eq - xv);
    }
    // dw scatter-add into replica (blk & 15): lane = dim, wave-uniform row.
    {
        float* dwr = ws + WS_DW + (size_t)(blk & 15) * 65536;
#pragma unroll 4
        for (int tt = 0; tt < 32; ++tt) {
            const int t = w * 32 + tt;
            const int kb = idx_sh[t];
            atomicAdd(&dwr[kb * 64 + lane], xs[t * 68 + lane]);
        }
    }
}

// Pure-store one-hot writer. grid 2048 x 256; 32 rows/block, f32x4/thread/row.
__global__ __launch_bounds__(256) void enc_write(const float* __restrict__ ws,
                                                 float* __restrict__ out) {
    const int tid = threadIdx.x;
    const int c0 = tid << 2;
    const int row0 = blockIdx.x << 5;
    const int* __restrict__ idxp = (const int*)(ws + WS_IDX);
    float* enc = out + 1 + (size_t)4194304;
    for (int r = 0; r < 32; ++r) {
        const int row = row0 + r;
        const int kb = idxp[row];
        f32x4 v;
        v[0] = (c0 == kb) ? 1.0f : 0.0f;
        v[1] = (c0 + 1 == kb) ? 1.0f : 0.0f;
        v[2] = (c0 + 2 == kb) ? 1.0f : 0.0f;
        v[3] = (c0 + 3 == kb) ? 1.0f : 0.0f;
        *(f32x4*)(enc + (size_t)row * 1024 + c0) = v;
    }
}

// new_cs (Laplace-smoothed, 16 count replicas) + loss. 1 block x 1024.
__global__ __launch_bounds__(1024) void fin_cs(const float* __restrict__ cs_in,
                                               float* __restrict__ out,
                                               const float* __restrict__ ws) {
    __shared__ float red[16];
    __shared__ float n_sh;
    const int tid = threadIdx.x;
    float cnt = 0.f;
#pragma unroll
    for (int p = 0; p < 16; ++p) cnt += ws[WS_COUNTS + p * 1024 + tid];
    const float raw = cs_in[tid] * DECAYF + ONEMF * cnt;
    const float s = wave_reduce_add(raw);
    if ((tid & 63) == 0) red[tid >> 6] = s;
    __syncthreads();
    if (tid == 0) {
        float n = 0.f;
#pragma unroll
        for (int i = 0; i < 16; ++i) n += red[i];
        n_sh = n;
        out[0] = 0.25f * ws[WS_SSE] * (1.0f / 4194304.0f);  // loss
    }
    __syncthreads();
    const float n = n_sh;
    out[71368705 + tid] = (raw + EPSF) / (n + 1024.0f * EPSF) * n;
}

// new_ema_weight and new_embedding (reduce 16 dw replicas). grid 256 x 256.
__global__ __launch_bounds__(256) void fin_w(const float* __restrict__ emaw,
                                             float* __restrict__ out,
                                             const float* __restrict__ ws) {
    const int i = blockIdx.x * 256 + threadIdx.x;
    float acc = 0.f;
#pragma unroll
    for (int p = 0; p < 16; ++p) acc += ws[WS_DW + p * 65536 + i];
    const float val = emaw[i] * DECAYF + ONEMF * acc;
    out[71369729 + i] = val;                               // new_ema_weight
    const float cs = out[71368705 + (i >> 6)];             // new_cs
    out[71303169 + i] = val / cs;                          // new_embedding
}

extern "C" void kernel_launch(void* const* d_in, const int* in_sizes, int n_in,
                              void* d_out, int out_size, void* d_ws, size_t ws_size,
                              hipStream_t stream) {
    const float* x    = (const float*)d_in[0];   // [16,64,64,64]
    const float* E    = (const float*)d_in[1];   // [1024,64]
    const float* cs   = (const float*)d_in[2];   // [1024]
    const float* emaw = (const float*)d_in[3];   // [1024,64]
    float* out = (float*)d_out;
    float* ws  = (float*)d_ws;

    prep_kernel<<<4160, 256, 0, stream>>>(E, ws);
    vq_main<<<512, 256, 0, stream>>>(x, E, out, ws);
    enc_write<<<2048, 256, 0, stream>>>(ws, out);
    fin_cs<<<1, 1024, 0, stream>>>(cs, out, ws);
    fin_w<<<256, 256, 0, stream>>>(emaw, out, ws);
}

// Round 6
// 419.026 us; speedup vs baseline: 1.1046x; 1.0093x over previous
//
#include <hip/hip_runtime.h>

#define HW 4096
#define DECAYF 0.99f
#define ONEMF 0.01f
#define EPSF 1e-5f
#define BIAS 192.0f

typedef __bf16 bf16x8 __attribute__((ext_vector_type(8)));
typedef float f32x4 __attribute__((ext_vector_type(4)));
typedef unsigned short ushort8 __attribute__((ext_vector_type(8)));

// ws float layout:
// [0, 1048576)            dw accumulator, 16 replicas of K*D
// [1048576, 1064960)      counts, 16 replicas of K
// [1064960, 1065984)      nchalf = -0.5*||e_k||^2
// [1065984]               sse
// [1066000, 1131536)      idx (int) per token, 65536
// [1131536, 1164304)      E_hi bf16 (ushort) [K][D]
// [1164304, 1197072)      E_lo bf16 (ushort)
#define WS_DW     0
#define WS_COUNTS 1048576
#define WS_NCHALF 1064960
#define WS_SSE    1065984
#define WS_IDX    1066000
#define WS_EHI    1131536
#define WS_ELO    1164304

__device__ __forceinline__ float wave_reduce_add(float v) {
#pragma unroll
    for (int o = 32; o > 0; o >>= 1) v += __shfl_xor(v, o, 64);
    return v;
}

__device__ __forceinline__ unsigned short bf_rne(float f) {
    unsigned int u = __float_as_uint(f);
    unsigned int r = u + 0x7fffu + ((u >> 16) & 1u);
    return (unsigned short)(r >> 16);
}

__device__ __forceinline__ unsigned med3u(unsigned a, unsigned b, unsigned c) {
    unsigned mn = a < b ? a : b;
    unsigned mx = a > b ? a : b;
    unsigned t = mx < c ? mx : c;
    return mn > t ? mn : t;
}

// Zero dw/counts (contiguous 1,064,960 floats) + sse; E split; nchalf.
// grid 4160 x 256.
__global__ __launch_bounds__(256) void prep_kernel(const float* __restrict__ E,
                                                   float* __restrict__ ws) {
    const int bid = blockIdx.x, tid = threadIdx.x;
    const int id = bid * 256 + tid;
    ws[id] = 0.0f;
    if (bid == 0 && tid == 0) ws[WS_SSE] = 0.0f;
    if (bid < 256) {
        const float v = E[id];
        const unsigned short h = bf_rne(v);
        const float hf = __uint_as_float((unsigned int)h << 16);
        const unsigned short l = bf_rne(v - hf);
        ((unsigned short*)(ws + WS_EHI))[id] = h;
        ((unsigned short*)(ws + WS_ELO))[id] = l;
        const float s = wave_reduce_add(v * v);
        if ((tid & 63) == 0) ws[WS_NCHALF + (id >> 6)] = -0.5f * s;
    }
}

// Main: grid 512 x 512 threads (8 waves). Block = 128 tokens.
// Wave w: token-group (w&3)*32..+32, code-half (w>>2)*512..+512.
__global__ __launch_bounds__(512, 4) void vq_main(const float* __restrict__ x,
                                                  const float* __restrict__ E,
                                                  float* __restrict__ out,
                                                  float* __restrict__ ws) {
    const int tid = threadIdx.x;
    const int lane = tid & 63;
    const int w = tid >> 6;
    const int wg = w & 3;              // token group
    const int kh = w >> 2;             // code half
    const int q = lane >> 4, m = lane & 15;
    const int blk = blockIdx.x;
    const int bb = blk >> 5;           // batch
    const int hw0 = (blk & 31) << 7;   // hw offset (128 tokens)
    const int tok0 = blk << 7;

    __shared__ float xs[128 * 68];
    __shared__ unsigned t1s[8][32][4], t2s[8][32][4];
    __shared__ int t1c[8][32][4], t2c[8][32][4];
    __shared__ int idx_sh[128];

    // Stage x tile (coalesced).
    {
        const float* xb = x + ((size_t)bb << 18) + hw0;
#pragma unroll
        for (int cc = 0; cc < 16; ++cc) {
            const int id = cc * 512 + tid;
            const int c = id >> 7, t = id & 127;
            xs[t * 68 + c] = xb[((size_t)c << 12) + t];
        }
    }
    __syncthreads();

    // A fragments: 2 row-tiles (tokens wg*32 + t*16 + m) x 2 K-slices x (hi,lo).
    bf16x8 Ah[2][2], Al[2][2];
#pragma unroll
    for (int t = 0; t < 2; ++t) {
        const int tok = wg * 32 + t * 16 + m;
#pragma unroll
        for (int s = 0; s < 2; ++s) {
            const float* p = &xs[tok * 68 + s * 32 + q * 8];
            ushort8 hu, lu;
#pragma unroll
            for (int j = 0; j < 8; ++j) {
                const float f = p[j];
                const unsigned short h = bf_rne(f);
                const float hf = __uint_as_float((unsigned int)h << 16);
                hu[j] = h;
                lu[j] = bf_rne(f - hf);
            }
            Ah[t][s] = __builtin_bit_cast(bf16x8, hu);
            Al[t][s] = __builtin_bit_cast(bf16x8, lu);
        }
    }

    const ushort8* __restrict__ Ehp = (const ushort8*)(ws + WS_EHI);
    const ushort8* __restrict__ Elp = (const ushort8*)(ws + WS_ELO);
    const float* __restrict__ ncp = ws + WS_NCHALF;

    // Packed top-2: fp32 bits of (score+BIAS) monotone-unsigned; low 6 bits = global ck.
    unsigned b1[2][4] = {{0,0,0,0},{0,0,0,0}}, b2[2][4] = {{0,0,0,0},{0,0,0,0}};

    const int ck0 = kh * 32;
    // Double-buffered B fragments (A = even ck, B = odd ck), 2-deep prefetch.
    const int codeA0 = ck0 * 16 + m, codeB0 = (ck0 + 1) * 16 + m;
    ushort8 hA0 = Ehp[codeA0 * 8 + q],     hA1 = Ehp[codeA0 * 8 + 4 + q];
    ushort8 lA0 = Elp[codeA0 * 8 + q],     lA1 = Elp[codeA0 * 8 + 4 + q];
    float   ncA = ncp[codeA0];
    ushort8 hB0 = Ehp[codeB0 * 8 + q],     hB1 = Ehp[codeB0 * 8 + 4 + q];
    ushort8 lB0 = Elp[codeB0 * 8 + q],     lB1 = Elp[codeB0 * 8 + 4 + q];
    float   ncB = ncp[codeB0];

    auto compute = [&](const ushort8& h0, const ushort8& h1, const ushort8& l0,
                       const ushort8& l1, float nc, int ckv) {
        const bf16x8 bh0 = __builtin_bit_cast(bf16x8, h0);
        const bf16x8 bh1 = __builtin_bit_cast(bf16x8, h1);
        const bf16x8 bl0 = __builtin_bit_cast(bf16x8, l0);
        const bf16x8 bl1 = __builtin_bit_cast(bf16x8, l1);
        const float base = nc + BIAS;
#pragma unroll
        for (int t = 0; t < 2; ++t) {
            f32x4 acc = {base, base, base, base};
            acc = __builtin_amdgcn_mfma_f32_16x16x32_bf16(Ah[t][0], bh0, acc, 0, 0, 0);
            acc = __builtin_amdgcn_mfma_f32_16x16x32_bf16(Ah[t][1], bh1, acc, 0, 0, 0);
            acc = __builtin_amdgcn_mfma_f32_16x16x32_bf16(Al[t][0], bh0, acc, 0, 0, 0);
            acc = __builtin_amdgcn_mfma_f32_16x16x32_bf16(Al[t][1], bh1, acc, 0, 0, 0);
            acc = __builtin_amdgcn_mfma_f32_16x16x32_bf16(Ah[t][0], bl0, acc, 0, 0, 0);
            acc = __builtin_amdgcn_mfma_f32_16x16x32_bf16(Ah[t][1], bl1, acc, 0, 0, 0);
#pragma unroll
            for (int r = 0; r < 4; ++r) {
                const unsigned p = (__float_as_uint(acc[r]) & ~63u) | (unsigned)ckv;
                b2[t][r] = med3u(b1[t][r], b2[t][r], p);
                b1[t][r] = b1[t][r] > p ? b1[t][r] : p;
            }
        }
    };

    for (int j2 = 0; j2 < 16; ++j2) {
        const int ckA = ck0 + 2 * j2;
        const ushort8 ch0 = hA0, ch1 = hA1, cl0 = lA0, cl1 = lA1; const float cnc = ncA;
        {
            const int nc_ = (j2 < 15) ? (ckA + 2) * 16 + m : codeA0;
            hA0 = Ehp[nc_ * 8 + q]; hA1 = Ehp[nc_ * 8 + 4 + q];
            lA0 = Elp[nc_ * 8 + q]; lA1 = Elp[nc_ * 8 + 4 + q];
            ncA = ncp[nc_];
        }
        compute(ch0, ch1, cl0, cl1, cnc, ckA);
        const ushort8 dh0 = hB0, dh1 = hB1, dl0 = lB0, dl1 = lB1; const float dnc = ncB;
        {
            const int nc_ = (j2 < 15) ? (ckA + 3) * 16 + m : codeB0;
            hB0 = Ehp[nc_ * 8 + q]; hB1 = Ehp[nc_ * 8 + 4 + q];
            lB0 = Elp[nc_ * 8 + q]; lB1 = Elp[nc_ * 8 + 4 + q];
            ncB = ncp[nc_];
        }
        compute(dh0, dh1, dl0, dl1, dnc, ckA + 1);
    }

    // Explicit codes, then shuffle pre-merge across m-groups of 4.
    int c1[2][4], c2[2][4];
#pragma unroll
    for (int t = 0; t < 2; ++t)
#pragma unroll
        for (int r = 0; r < 4; ++r) {
            c1[t][r] = (int)((b1[t][r] & 63u) << 4) | m;
            c2[t][r] = (int)((b2[t][r] & 63u) << 4) | m;
        }
#pragma unroll
    for (int d = 1; d < 4; d <<= 1) {
#pragma unroll
        for (int t = 0; t < 2; ++t)
#pragma unroll
            for (int r = 0; r < 4; ++r) {
                const unsigned o1 = __shfl_xor(b1[t][r], d, 64);
                const int      oc1 = __shfl_xor(c1[t][r], d, 64);
                const unsigned o2 = __shfl_xor(b2[t][r], d, 64);
                const int      oc2 = __shfl_xor(c2[t][r], d, 64);
                const bool win = o1 > b1[t][r];
                const unsigned n1 = win ? o1 : b1[t][r]; const int nc1 = win ? oc1 : c1[t][r];
                const unsigned ls = win ? b1[t][r] : o1; const int lc = win ? c1[t][r] : oc1;
                const unsigned os = win ? o2 : b2[t][r]; const int oc = win ? oc2 : c2[t][r];
                const bool sec = ls > os;
                b1[t][r] = n1; c1[t][r] = nc1;
                b2[t][r] = sec ? ls : os; c2[t][r] = sec ? lc : oc;
            }
    }
    if ((m & 3) == 0) {
        const int g = m >> 2;
#pragma unroll
        for (int t = 0; t < 2; ++t)
#pragma unroll
            for (int r = 0; r < 4; ++r) {
                const int trow = t * 16 + q * 4 + r;
                t1s[w][trow][g] = b1[t][r]; t1c[w][trow][g] = c1[t][r];
                t2s[w][trow][g] = b2[t][r]; t2c[w][trow][g] = c2[t][r];
            }
    }
    __syncthreads();

    // Final merge (waves 0-3, lanes 0-31): 16 candidates, then fp64 re-rank.
    float dval = 0.0f;
    if (w < 4) {
        if (lane < 32) {
            const int trow = lane;
            unsigned s1 = 0, s2 = 0;
            int cc1 = 0, cc2 = 0;
#pragma unroll
            for (int h = 0; h < 2; ++h) {
                const int ww = wg + h * 4;
#pragma unroll
                for (int g = 0; g < 4; ++g) {
                    const unsigned a = t1s[ww][trow][g]; const int ac = t1c[ww][trow][g];
                    if (a > s1) { s2 = s1; cc2 = cc1; s1 = a; cc1 = ac; }
                    else if (a > s2) { s2 = a; cc2 = ac; }
                    const unsigned bs = t2s[ww][trow][g]; const int bc = t2c[ww][trow][g];
                    if (bs > s2) { s2 = bs; cc2 = bc; }
                }
            }
            const int tokL = wg * 32 + lane;
            const int ca = cc1 < cc2 ? cc1 : cc2;
            const int cb = cc1 < cc2 ? cc2 : cc1;
            const f32x4* Ea4 = (const f32x4*)(E + ca * 64);
            const f32x4* Eb4 = (const f32x4*)(E + cb * 64);
            const f32x4* xr4 = (const f32x4*)(&xs[tokL * 68]);
            double sa = 0, ea = 0, sb = 0, eb = 0, x2 = 0;
#pragma unroll 4
            for (int c4 = 0; c4 < 16; ++c4) {
                const f32x4 ev = Ea4[c4], fv = Eb4[c4], xv4 = xr4[c4];
#pragma unroll
                for (int j = 0; j < 4; ++j) {
                    const double xv = (double)xv4[j];
                    const double va = (double)ev[j], vb = (double)fv[j];
                    sa += xv * va; ea += va * va;
                    sb += xv * vb; eb += vb * vb;
                    x2 += xv * xv;
                }
            }
            const double qa = ea - 2.0 * sa;
            const double qb = eb - 2.0 * sb;
            int best; double qq;
            if (qb < qa) { best = cb; qq = qb; } else { best = ca; qq = qa; }
            idx_sh[tokL] = best;
            ((int*)(ws + WS_IDX))[tok0 + tokL] = best;
            float dd = (float)(qq + x2);
            dval = dd < 0.f ? 0.f : dd;
            atomicAdd(&ws[WS_COUNTS + (blk & 15) * 1024 + best], 1.0f);
        }
        const float ssum = wave_reduce_add(dval);
        if (lane == 0) atomicAdd(&ws[WS_SSE], ssum);
    }
    __syncthreads();

    // q_st output (reference order: x + (e - x)).
    float* outq = out + 1;
#pragma unroll
    for (int cc = 0; cc < 16; ++cc) {
        const int id = cc * 512 + tid;
        const int c = id >> 7, t = id & 127;
        const int kb = idx_sh[t];
        const float xv = xs[t * 68 + c];
        const float eq = E[kb * 64 + c];
        outq[((size_t)(bb * 64 + c) << 12) + hw0 + t] = xv + (eq - xv);
    }
    // dw scatter-add into replica (blk & 15): lane = dim, wave-uniform row.
    {
        float* dwr = ws + WS_DW + (size_t)(blk & 15) * 65536;
#pragma unroll 4
        for (int tt = 0; tt < 16; ++tt) {
            const int t = w * 16 + tt;
            const int kb = idx_sh[t];
            atomicAdd(&dwr[kb * 64 + lane], xs[t * 68 + lane]);
        }
    }
}

// Pure-store one-hot writer. grid 2048 x 256; 32 rows/block, f32x4/thread/row.
__global__ __launch_bounds__(256) void enc_write(const float* __restrict__ ws,
                                                 float* __restrict__ out) {
    const int tid = threadIdx.x;
    const int c0 = tid << 2;
    const int row0 = blockIdx.x << 5;
    const int* __restrict__ idxp = (const int*)(ws + WS_IDX);
    float* enc = out + 1 + (size_t)4194304;
    for (int r = 0; r < 32; ++r) {
        const int row = row0 + r;
        const int kb = idxp[row];
        f32x4 v;
        v[0] = (c0 == kb) ? 1.0f : 0.0f;
        v[1] = (c0 + 1 == kb) ? 1.0f : 0.0f;
        v[2] = (c0 + 2 == kb) ? 1.0f : 0.0f;
        v[3] = (c0 + 3 == kb) ? 1.0f : 0.0f;
        *(f32x4*)(enc + (size_t)row * 1024 + c0) = v;
    }
}

// new_cs (Laplace-smoothed, 16 count replicas) + loss. 1 block x 1024.
__global__ __launch_bounds__(1024) void fin_cs(const float* __restrict__ cs_in,
                                               float* __restrict__ out,
                                               const float* __restrict__ ws) {
    __shared__ float red[16];
    __shared__ float n_sh;
    const int tid = threadIdx.x;
    float cnt = 0.f;
#pragma unroll
    for (int p = 0; p < 16; ++p) cnt += ws[WS_COUNTS + p * 1024 + tid];
    const float raw = cs_in[tid] * DECAYF + ONEMF * cnt;
    const float s = wave_reduce_add(raw);
    if ((tid & 63) == 0) red[tid >> 6] = s;
    __syncthreads();
    if (tid == 0) {
        float n = 0.f;
#pragma unroll
        for (int i = 0; i < 16; ++i) n += red[i];
        n_sh = n;
        out[0] = 0.25f * ws[WS_SSE] * (1.0f / 4194304.0f);
    }
    __syncthreads();
    const float n = n_sh;
    out[71368705 + tid] = (raw + EPSF) / (n + 1024.0f * EPSF) * n;
}

// new_ema_weight and new_embedding (reduce 16 dw replicas). grid 256 x 256.
__global__ __launch_bounds__(256) void fin_w(const float* __restrict__ emaw,
                                             float* __restrict__ out,
                                             const float* __restrict__ ws) {
    const int i = blockIdx.x * 256 + threadIdx.x;
    float acc = 0.f;
#pragma unroll
    for (int p = 0; p < 16; ++p) acc += ws[WS_DW + p * 65536 + i];
    const float val = emaw[i] * DECAYF + ONEMF * acc;
    out[71369729 + i] = val;
    const float cs = out[71368705 + (i >> 6)];
    out[71303169 + i] = val / cs;
}

extern "C" void kernel_launch(void* const* d_in, const int* in_sizes, int n_in,
                              void* d_out, int out_size, void* d_ws, size_t ws_size,
                              hipStream_t stream) {
    const float* x    = (const float*)d_in[0];
    const float* E    = (const float*)d_in[1];
    const float* cs   = (const float*)d_in[2];
    const float* emaw = (const float*)d_in[3];
    float* out = (float*)d_out;
    float* ws  = (float*)d_ws;

    prep_kernel<<<4160, 256, 0, stream>>>(E, ws);
    vq_main<<<512, 512, 0, stream>>>(x, E, out, ws);
    enc_write<<<2048, 256, 0, stream>>>(ws, out);
    fin_cs<<<1, 1024, 0, stream>>>(cs, out, ws);
    fin_w<<<256, 256, 0, stream>>>(emaw, out, ws);
}